// Round 6
// baseline (492.958 us; speedup 1.0000x reference)
//
#include <hip/hip_runtime.h>

typedef unsigned short u16;
typedef __attribute__((ext_vector_type(4))) float f4;
typedef __attribute__((ext_vector_type(8))) short s8v;    // 8 x bf16 MFMA frag (4 VGPRs)
typedef __attribute__((ext_vector_type(4))) unsigned short u16x4;

#define DEVINL __device__ __forceinline__

DEVINL float b2f(u16 u) { union { unsigned i; float f; } x; x.i = ((unsigned)u) << 16; return x.f; }
DEVINL u16 f2b(float f) {
  union { float f; unsigned i; } x; x.f = f;
  unsigned r = 0x7FFFu + ((x.i >> 16) & 1u);
  return (u16)((x.i + r) >> 16);
}

// ---------------- transpose + fp32->bf16 cast: out[C,R] = cast(in[R,C]^T) ----------------
__global__ __launch_bounds__(256) void k_transpose(const float* __restrict__ in,
                                                   u16* __restrict__ out, int R, int C) {
  __shared__ float t[32][33];
  int tx = threadIdx.x & 31, ty = threadIdx.x >> 5;
  int c0 = blockIdx.x * 32, r0 = blockIdx.y * 32;
#pragma unroll
  for (int i = 0; i < 32; i += 8)
    t[ty + i][tx] = in[(long)(r0 + ty + i) * C + (c0 + tx)];
  __syncthreads();
#pragma unroll
  for (int i = 0; i < 32; i += 8)
    out[(long)(c0 + ty + i) * R + (r0 + tx)] = f2b(t[tx][ty + i]);
}

// ---------------- bf16 V transpose: v [B,S,H,D] -> vt [B,H,D,S] ----------------
__global__ __launch_bounds__(256) void k_vtrans(const u16* __restrict__ v, u16* __restrict__ vt) {
  __shared__ u16 t[64][72];
  int bh = blockIdx.x, b = bh >> 4, h = bh & 15;
  int s0 = blockIdx.y * 64;
  int tid = threadIdx.x;
#pragma unroll
  for (int p = 0; p < 2; ++p) {
    int idx = p * 256 + tid;
    int sl = idx >> 3, c8 = (idx & 7) * 8;
    *(s8v*)(&t[sl][c8]) = *(const s8v*)(v + (((long)(b * 1024 + s0 + sl) * 16 + h) * 64) + c8);
  }
  __syncthreads();
#pragma unroll
  for (int p = 0; p < 2; ++p) {
    int idx = p * 256 + tid;
    int d = idx >> 3, c8 = (idx & 7) * 8;
    s8v o;
#pragma unroll
    for (int e = 0; e < 8; ++e) o[e] = (short)t[c8 + e][d];
    *(s8v*)(vt + ((long)bh * 64 + d) * 1024 + s0 + c8) = o;
  }
}

// ---------------- LayerNorm over E=1024, one row per block, bf16 out ----------------
__global__ __launch_bounds__(256) void k_layernorm(const float* __restrict__ x,
                                                   const float* __restrict__ g,
                                                   const float* __restrict__ be,
                                                   u16* __restrict__ out) {
  long row = blockIdx.x;
  int tid = threadIdx.x;
  f4 v = ((const f4*)(x + row * 1024))[tid];
  float s = v[0] + v[1] + v[2] + v[3];
  float s2 = v[0] * v[0] + v[1] * v[1] + v[2] * v[2] + v[3] * v[3];
#pragma unroll
  for (int off = 32; off > 0; off >>= 1) {
    s += __shfl_down(s, off, 64);
    s2 += __shfl_down(s2, off, 64);
  }
  __shared__ float red[8];
  int wv = tid >> 6, ln = tid & 63;
  if (ln == 0) { red[wv] = s; red[4 + wv] = s2; }
  __syncthreads();
  s = red[0] + red[1] + red[2] + red[3];
  s2 = red[4] + red[5] + red[6] + red[7];
  float mean = s * (1.0f / 1024.0f);
  float var = s2 * (1.0f / 1024.0f) - mean * mean;
  float rs = rsqrtf(var + 1e-5f);
  f4 gg = ((const f4*)g)[tid];
  f4 bb = ((const f4*)be)[tid];
  u16x4 o;
#pragma unroll
  for (int i = 0; i < 4; ++i) o[i] = f2b((v[i] - mean) * rs * gg[i] + bb[i]);
  ((u16x4*)(out + row * 1024))[tid] = o;
}

// ---------------- QKV: [131072,64] @ [64,64] x3, MFMA 16x16x32 bf16 ----------------
__global__ __launch_bounds__(256) void k_qkv(const u16* __restrict__ nx, const u16* __restrict__ WqT,
                                             const u16* __restrict__ WkT, const u16* __restrict__ WvT,
                                             u16* __restrict__ q, u16* __restrict__ k,
                                             u16* __restrict__ v) {
  int tid = threadIdx.x, lane = tid & 63, wave = tid >> 6;
  int quad = lane >> 4, l16 = lane & 15;
  long rbase = (long)blockIdx.x * 64 + wave * 16;
  s8v a0 = *(const s8v*)(nx + (rbase + l16) * 64 + quad * 8);
  s8v a1 = *(const s8v*)(nx + (rbase + l16) * 64 + 32 + quad * 8);
  const u16* Ws[3] = {WqT, WkT, WvT};
  u16* Os[3] = {q, k, v};
#pragma unroll
  for (int t = 0; t < 3; ++t) {
#pragma unroll
    for (int j = 0; j < 4; ++j) {
      s8v b0 = *(const s8v*)(Ws[t] + (j * 16 + l16) * 64 + quad * 8);
      s8v b1 = *(const s8v*)(Ws[t] + (j * 16 + l16) * 64 + 32 + quad * 8);
      f4 acc = {0.f, 0.f, 0.f, 0.f};
      acc = __builtin_amdgcn_mfma_f32_16x16x32_bf16(a0, b0, acc, 0, 0, 0);
      acc = __builtin_amdgcn_mfma_f32_16x16x32_bf16(a1, b1, acc, 0, 0, 0);
#pragma unroll
      for (int r = 0; r < 4; ++r)
        Os[t][(rbase + quad * 4 + r) * 64 + j * 16 + l16] = f2b(acc[r]);
    }
  }
}

// ---------------- MFMA flash attention (causal) ----------------
// q,k: [B,S,H,D] bf16; vt: [B,H,D,S] bf16 (pre-transposed). o: [B,S,H,D].
__global__ __launch_bounds__(256) void k_attn_mfma(const u16* __restrict__ q,
                                                   const u16* __restrict__ kk,
                                                   const u16* __restrict__ vt,
                                                   u16* __restrict__ o) {
  constexpr int LDK = 72;  // row stride (u16): 144 B -> b128-aligned rows, non-pow2 banks
  __shared__ u16 Ks[64 * LDK];      // [key][d]
  __shared__ u16 Vt[64 * LDK];      // [d][key]
  __shared__ u16 Ps[4][16 * LDK];   // per-wave P [qrow][key]
  int tid = threadIdx.x, lane = tid & 63, wave = tid >> 6;
  int quad = lane >> 4, l16 = lane & 15;
  int b = blockIdx.x >> 4, h = blockIdx.x & 15;
  int qi = (int)gridDim.y - 1 - (int)blockIdx.y;  // heavy q-tiles dispatch first
  int q0 = qi * 64 + wave * 16;

  const u16* qp = q + (((long)(b * 1024 + q0 + l16)) * 16 + h) * 64;
  s8v aq0 = *(const s8v*)(qp + quad * 8);
  s8v aq1 = *(const s8v*)(qp + 32 + quad * 8);

  f4 O[4];
  float m_[4], l_[4];
#pragma unroll
  for (int jd = 0; jd < 4; ++jd) O[jd] = f4{0.f, 0.f, 0.f, 0.f};
#pragma unroll
  for (int r = 0; r < 4; ++r) { m_[r] = -__builtin_inff(); l_[r] = 0.f; }

  for (int kt = 0; kt <= qi; ++kt) {
    __syncthreads();  // protect Ks/Vt reuse across tiles
#pragma unroll
    for (int p = 0; p < 2; ++p) {
      int idx = p * 256 + tid;
      int row = idx >> 3, c8 = (idx & 7) * 8;
      *(s8v*)(Ks + row * LDK + c8) =
          *(const s8v*)(kk + (((long)(b * 1024 + kt * 64 + row)) * 16 + h) * 64 + c8);
      *(s8v*)(Vt + row * LDK + c8) =
          *(const s8v*)(vt + ((long)blockIdx.x * 64 + row) * 1024 + kt * 64 + c8);
    }
    __syncthreads();

    // ---- S = Q K^T ----
    f4 sf[4];
#pragma unroll
    for (int jn = 0; jn < 4; ++jn) {
      s8v b0 = *(const s8v*)(Ks + (jn * 16 + l16) * LDK + quad * 8);
      s8v b1 = *(const s8v*)(Ks + (jn * 16 + l16) * LDK + 32 + quad * 8);
      f4 acc = f4{0.f, 0.f, 0.f, 0.f};
      acc = __builtin_amdgcn_mfma_f32_16x16x32_bf16(aq0, b0, acc, 0, 0, 0);
      acc = __builtin_amdgcn_mfma_f32_16x16x32_bf16(aq1, b1, acc, 0, 0, 0);
      sf[jn] = acc;
    }
    bool diag = (kt == qi);
    float rm[4];
#pragma unroll
    for (int r = 0; r < 4; ++r) rm[r] = -__builtin_inff();
#pragma unroll
    for (int jn = 0; jn < 4; ++jn)
#pragma unroll
      for (int r = 0; r < 4; ++r) {
        float v = sf[jn][r] * 0.03125f;
        if (diag && (jn * 16 + l16 > wave * 16 + quad * 4 + r)) v = -__builtin_inff();
        sf[jn][r] = v;
        rm[r] = fmaxf(rm[r], v);
      }
#pragma unroll
    for (int off = 1; off < 16; off <<= 1)
#pragma unroll
      for (int r = 0; r < 4; ++r) rm[r] = fmaxf(rm[r], __shfl_xor(rm[r], off, 64));
    float alpha[4], rs[4];
#pragma unroll
    for (int r = 0; r < 4; ++r) {
      float mn = fmaxf(m_[r], rm[r]);
      alpha[r] = __expf(m_[r] - mn);
      m_[r] = mn;
      rs[r] = 0.f;
    }
#pragma unroll
    for (int jn = 0; jn < 4; ++jn)
#pragma unroll
      for (int r = 0; r < 4; ++r) {
        float p = __expf(sf[jn][r] - m_[r]);
        rs[r] += p;
        Ps[wave][(quad * 4 + r) * LDK + jn * 16 + l16] = f2b(p);
      }
#pragma unroll
    for (int off = 1; off < 16; off <<= 1)
#pragma unroll
      for (int r = 0; r < 4; ++r) rs[r] += __shfl_xor(rs[r], off, 64);
#pragma unroll
    for (int r = 0; r < 4; ++r) l_[r] = l_[r] * alpha[r] + rs[r];
#pragma unroll
    for (int jd = 0; jd < 4; ++jd)
#pragma unroll
      for (int r = 0; r < 4; ++r) O[jd][r] *= alpha[r];
    asm volatile("s_waitcnt lgkmcnt(0)" ::: "memory");
    s8v p0 = *(const s8v*)(&Ps[wave][l16 * LDK + quad * 8]);
    s8v p1 = *(const s8v*)(&Ps[wave][l16 * LDK + 32 + quad * 8]);
#pragma unroll
    for (int jd = 0; jd < 4; ++jd) {
      s8v b0 = *(const s8v*)(Vt + (jd * 16 + l16) * LDK + quad * 8);
      s8v b1 = *(const s8v*)(Vt + (jd * 16 + l16) * LDK + 32 + quad * 8);
      O[jd] = __builtin_amdgcn_mfma_f32_16x16x32_bf16(p0, b0, O[jd], 0, 0, 0);
      O[jd] = __builtin_amdgcn_mfma_f32_16x16x32_bf16(p1, b1, O[jd], 0, 0, 0);
    }
  }
#pragma unroll
  for (int r = 0; r < 4; ++r) {
    float inv = 1.0f / l_[r];
    u16* op = o + (((long)(b * 1024 + q0 + quad * 4 + r)) * 16 + h) * 64;
#pragma unroll
    for (int jd = 0; jd < 4; ++jd) op[jd * 16 + l16] = f2b(O[jd][r] * inv);
  }
}

// ---------------- 128x128 GEMM, register-staged pipeline (AITER-style) ----------------
// A[M,K] bf16, BT[N,K] bf16, fp32 acc.
// EPI=1: out = bf16(relu(acc+bias));  EPI=2: out = fp32(resid + acc + bias)
// K-loop: global_load tile k+1 into VGPRs; ds_read + 16 MFMA on tile k; ds_write
// tile k+1 (compiler inserts the precise vmcnt wait HERE, after the MFMA phase);
// then a custom lgkm-only barrier — global loads stay in flight across it,
// unlike __syncthreads() which drains vmcnt(0) (the m97-structure stall).
// Single collective barrier/iter is race-free: lgkmcnt(0) retires each wave's
// ds_reads before it arrives, so post-barrier writes to the other buffer can't
// overtake any wave's reads.
template <int EPI>
__global__ __launch_bounds__(256) void k_gemm_bt(const u16* __restrict__ A, const u16* __restrict__ BT,
                                                 const float* __restrict__ bias,
                                                 const float* __restrict__ resid,
                                                 void* __restrict__ outp, int M, int N, int K) {
  __shared__ u16 sA[2][128 * 32];
  __shared__ u16 sB[2][128 * 32];
  int tid = threadIdx.x, lane = tid & 63, wave = tid >> 6;
  int quad = lane >> 4, l16 = lane & 15;
  int wm = wave >> 1, wn = wave & 1;
  long bm = blockIdx.x, bn = blockIdx.y;
  int srow = tid >> 2, scol = (tid & 3) * 8;  // each thread stages rows {srow, srow+64}, 16 B
  const u16* ga = A + (bm * 128 + srow) * (long)K + scol;
  const u16* gb = BT + (bn * 128 + srow) * (long)K + scol;
  int so = srow * 32 + scol;  // LDS element offset for this thread's 16 B chunk

  f4 acc[4][4];
#pragma unroll
  for (int i = 0; i < 4; ++i)
#pragma unroll
    for (int j = 0; j < 4; ++j) acc[i][j] = f4{0.f, 0.f, 0.f, 0.f};

  // prologue: tile 0 through registers into buf 0
  s8v ra0 = *(const s8v*)(ga);
  s8v ra1 = *(const s8v*)(ga + 64 * (long)K);
  s8v rb0 = *(const s8v*)(gb);
  s8v rb1 = *(const s8v*)(gb + 64 * (long)K);
  *(s8v*)(&sA[0][so]) = ra0;
  *(s8v*)(&sA[0][64 * 32 + so]) = ra1;
  *(s8v*)(&sB[0][so]) = rb0;
  *(s8v*)(&sB[0][64 * 32 + so]) = rb1;
  __syncthreads();

  for (int k0 = 0; k0 < K; k0 += 32) {
    int cur = (k0 >> 5) & 1;
    int k1 = k0 + 32;
    if (k1 < K) {  // issue next tile's global loads (in flight through MFMA phase + barrier)
      ra0 = *(const s8v*)(ga + k1);
      ra1 = *(const s8v*)(ga + 64 * (long)K + k1);
      rb0 = *(const s8v*)(gb + k1);
      rb1 = *(const s8v*)(gb + 64 * (long)K + k1);
    }
    const u16* cA = sA[cur];
    const u16* cB = sB[cur];
    s8v aF[4], bF[4];
#pragma unroll
    for (int i = 0; i < 4; ++i)
      aF[i] = *(const s8v*)(cA + (wm * 64 + i * 16 + l16) * 32 + quad * 8);
#pragma unroll
    for (int j = 0; j < 4; ++j)
      bF[j] = *(const s8v*)(cB + (wn * 64 + j * 16 + l16) * 32 + quad * 8);
#pragma unroll
    for (int i = 0; i < 4; ++i)
#pragma unroll
      for (int j = 0; j < 4; ++j)
        acc[i][j] = __builtin_amdgcn_mfma_f32_16x16x32_bf16(aF[i], bF[j], acc[i][j], 0, 0, 0);
    if (k1 < K) {
      int nxt = cur ^ 1;
      *(s8v*)(&sA[nxt][so]) = ra0;          // compiler waits vmcnt here (post-MFMA)
      *(s8v*)(&sA[nxt][64 * 32 + so]) = ra1;
      *(s8v*)(&sB[nxt][so]) = rb0;
      *(s8v*)(&sB[nxt][64 * 32 + so]) = rb1;
      asm volatile("s_waitcnt lgkmcnt(0)\n\ts_barrier" ::: "memory");  // no vmcnt drain
    }
  }

#pragma unroll
  for (int i = 0; i < 4; ++i) {
#pragma unroll
    for (int j = 0; j < 4; ++j) {
      long row = bm * 128 + wm * 64 + i * 16 + quad * 4;
      int col = (int)bn * 128 + wn * 64 + j * 16 + l16;
      float bcol = bias[col];
#pragma unroll
      for (int r = 0; r < 4; ++r) {
        float val = acc[i][j][r] + bcol;
        if (EPI == 1) {
          ((u16*)outp)[(row + r) * (long)N + col] = f2b(val > 0.f ? val : 0.f);
        } else {
          ((float*)outp)[(row + r) * (long)N + col] = resid[(row + r) * (long)N + col] + val;
        }
      }
    }
  }
}

extern "C" void kernel_launch(void* const* d_in, const int* in_sizes, int n_in, void* d_out,
                              int out_size, void* d_ws, size_t ws_size, hipStream_t stream) {
  const float* x = (const float*)d_in[0];
  const float* Wq = (const float*)d_in[1];
  const float* Wk = (const float*)d_in[2];
  const float* Wv = (const float*)d_in[3];
  const float* Wo = (const float*)d_in[4];
  const float* bo = (const float*)d_in[5];
  const float* W1 = (const float*)d_in[6];
  const float* b1 = (const float*)d_in[7];
  const float* W2 = (const float*)d_in[8];
  const float* b2 = (const float*)d_in[9];
  const float* g1 = (const float*)d_in[10];
  const float* be1 = (const float*)d_in[11];
  const float* g2 = (const float*)d_in[12];
  const float* be2 = (const float*)d_in[13];

  char* ws = (char*)d_ws;
  const size_t MB = 1ull << 20;
  u16* nx = (u16*)(ws + 0);            // 16 MB  LN1 out; reused as attn out
  u16* qb = (u16*)(ws + 16 * MB);      // 16 MB  q; reused as nx2
  u16* kb = (u16*)(ws + 32 * MB);      // 16 MB
  u16* vb = (u16*)(ws + 48 * MB);      // 16 MB
  float* x1 = (float*)(ws + 64 * MB);  // 32 MB  attn-sublayer output (fp32 residual)
  u16* h1 = (u16*)(ws + 96 * MB);      // 64 MB  MLP hidden (after attn)
  u16* vtr = (u16*)(ws + 96 * MB);     // 16 MB  V^T [B,H,D,S]; dead before h1 is written
  u16* WoT = (u16*)(ws + 160 * MB);    // 2 MB
  u16* W1T = (u16*)(ws + 162 * MB);    // 8 MB
  u16* W2T = (u16*)(ws + 170 * MB);    // 8 MB
  u16* WqT = (u16*)(ws + 178 * MB);
  u16* WkT = WqT + 64 * 64;
  u16* WvT = WkT + 64 * 64;
  u16* ob = nx;
  u16* nx2 = qb;

  k_transpose<<<dim3(32, 32), 256, 0, stream>>>(Wo, WoT, 1024, 1024);
  k_transpose<<<dim3(128, 32), 256, 0, stream>>>(W1, W1T, 1024, 4096);
  k_transpose<<<dim3(32, 128), 256, 0, stream>>>(W2, W2T, 4096, 1024);
  k_transpose<<<dim3(2, 2), 256, 0, stream>>>(Wq, WqT, 64, 64);
  k_transpose<<<dim3(2, 2), 256, 0, stream>>>(Wk, WkT, 64, 64);
  k_transpose<<<dim3(2, 2), 256, 0, stream>>>(Wv, WvT, 64, 64);

  k_layernorm<<<8192, 256, 0, stream>>>(x, g1, be1, nx);
  k_qkv<<<2048, 256, 0, stream>>>(nx, WqT, WkT, WvT, qb, kb, vb);
  k_vtrans<<<dim3(128, 16), 256, 0, stream>>>(vb, vtr);
  k_attn_mfma<<<dim3(128, 16), 256, 0, stream>>>(qb, kb, vtr, ob);
  k_gemm_bt<2><<<dim3(64, 8), 256, 0, stream>>>(ob, WoT, bo, x, x1, 8192, 1024, 1024);

  k_layernorm<<<8192, 256, 0, stream>>>(x1, g2, be2, nx2);
  k_gemm_bt<1><<<dim3(64, 32), 256, 0, stream>>>(nx2, W1T, b1, nullptr, h1, 8192, 4096, 1024);
  k_gemm_bt<2><<<dim3(64, 8), 256, 0, stream>>>(h1, W2T, b2, x1, d_out, 8192, 1024, 4096);
}

// Round 7
// 456.974 us; speedup vs baseline: 1.0787x; 1.0787x over previous
//
#include <hip/hip_runtime.h>

typedef unsigned short u16;
typedef __attribute__((ext_vector_type(4))) float f4;
typedef __attribute__((ext_vector_type(8))) short s8v;    // 8 x bf16 MFMA frag (4 VGPRs)
typedef __attribute__((ext_vector_type(4))) unsigned short u16x4;

#define DEVINL __device__ __forceinline__

DEVINL float b2f(u16 u) { union { unsigned i; float f; } x; x.i = ((unsigned)u) << 16; return x.f; }
DEVINL u16 f2b(float f) {
  union { float f; unsigned i; } x; x.f = f;
  unsigned r = 0x7FFFu + ((x.i >> 16) & 1u);
  return (u16)((x.i + r) >> 16);
}

#define GLD_LDS16(g, l)                                                        \
  __builtin_amdgcn_global_load_lds((__attribute__((address_space(1))) void*)(g), \
                                   (__attribute__((address_space(3))) void*)(l), 16, 0, 0)

// ---------------- transpose + fp32->bf16 cast: out[C,R] = cast(in[R,C]^T) ----------------
__global__ __launch_bounds__(256) void k_transpose(const float* __restrict__ in,
                                                   u16* __restrict__ out, int R, int C) {
  __shared__ float t[32][33];
  int tx = threadIdx.x & 31, ty = threadIdx.x >> 5;
  int c0 = blockIdx.x * 32, r0 = blockIdx.y * 32;
#pragma unroll
  for (int i = 0; i < 32; i += 8)
    t[ty + i][tx] = in[(long)(r0 + ty + i) * C + (c0 + tx)];
  __syncthreads();
#pragma unroll
  for (int i = 0; i < 32; i += 8)
    out[(long)(c0 + ty + i) * R + (r0 + tx)] = f2b(t[tx][ty + i]);
}

// ---------------- bf16 V transpose: v [B,S,H,D] -> vt [B,H,D,S] ----------------
__global__ __launch_bounds__(256) void k_vtrans(const u16* __restrict__ v, u16* __restrict__ vt) {
  __shared__ u16 t[64][72];
  int bh = blockIdx.x, b = bh >> 4, h = bh & 15;
  int s0 = blockIdx.y * 64;
  int tid = threadIdx.x;
#pragma unroll
  for (int p = 0; p < 2; ++p) {
    int idx = p * 256 + tid;
    int sl = idx >> 3, c8 = (idx & 7) * 8;
    *(s8v*)(&t[sl][c8]) = *(const s8v*)(v + (((long)(b * 1024 + s0 + sl) * 16 + h) * 64) + c8);
  }
  __syncthreads();
#pragma unroll
  for (int p = 0; p < 2; ++p) {
    int idx = p * 256 + tid;
    int d = idx >> 3, c8 = (idx & 7) * 8;
    s8v o;
#pragma unroll
    for (int e = 0; e < 8; ++e) o[e] = (short)t[c8 + e][d];
    *(s8v*)(vt + ((long)bh * 64 + d) * 1024 + s0 + c8) = o;
  }
}

// ---------------- LayerNorm over E=1024, one row per block, bf16 out ----------------
__global__ __launch_bounds__(256) void k_layernorm(const float* __restrict__ x,
                                                   const float* __restrict__ g,
                                                   const float* __restrict__ be,
                                                   u16* __restrict__ out) {
  long row = blockIdx.x;
  int tid = threadIdx.x;
  f4 v = ((const f4*)(x + row * 1024))[tid];
  float s = v[0] + v[1] + v[2] + v[3];
  float s2 = v[0] * v[0] + v[1] * v[1] + v[2] * v[2] + v[3] * v[3];
#pragma unroll
  for (int off = 32; off > 0; off >>= 1) {
    s += __shfl_down(s, off, 64);
    s2 += __shfl_down(s2, off, 64);
  }
  __shared__ float red[8];
  int wv = tid >> 6, ln = tid & 63;
  if (ln == 0) { red[wv] = s; red[4 + wv] = s2; }
  __syncthreads();
  s = red[0] + red[1] + red[2] + red[3];
  s2 = red[4] + red[5] + red[6] + red[7];
  float mean = s * (1.0f / 1024.0f);
  float var = s2 * (1.0f / 1024.0f) - mean * mean;
  float rs = rsqrtf(var + 1e-5f);
  f4 gg = ((const f4*)g)[tid];
  f4 bb = ((const f4*)be)[tid];
  u16x4 o;
#pragma unroll
  for (int i = 0; i < 4; ++i) o[i] = f2b((v[i] - mean) * rs * gg[i] + bb[i]);
  ((u16x4*)(out + row * 1024))[tid] = o;
}

// ---------------- QKV: [131072,64] @ [64,64] x3, MFMA 16x16x32 bf16 ----------------
__global__ __launch_bounds__(256) void k_qkv(const u16* __restrict__ nx, const u16* __restrict__ WqT,
                                             const u16* __restrict__ WkT, const u16* __restrict__ WvT,
                                             u16* __restrict__ q, u16* __restrict__ k,
                                             u16* __restrict__ v) {
  int tid = threadIdx.x, lane = tid & 63, wave = tid >> 6;
  int quad = lane >> 4, l16 = lane & 15;
  long rbase = (long)blockIdx.x * 64 + wave * 16;
  s8v a0 = *(const s8v*)(nx + (rbase + l16) * 64 + quad * 8);
  s8v a1 = *(const s8v*)(nx + (rbase + l16) * 64 + 32 + quad * 8);
  const u16* Ws[3] = {WqT, WkT, WvT};
  u16* Os[3] = {q, k, v};
#pragma unroll
  for (int t = 0; t < 3; ++t) {
#pragma unroll
    for (int j = 0; j < 4; ++j) {
      s8v b0 = *(const s8v*)(Ws[t] + (j * 16 + l16) * 64 + quad * 8);
      s8v b1 = *(const s8v*)(Ws[t] + (j * 16 + l16) * 64 + 32 + quad * 8);
      f4 acc = {0.f, 0.f, 0.f, 0.f};
      acc = __builtin_amdgcn_mfma_f32_16x16x32_bf16(a0, b0, acc, 0, 0, 0);
      acc = __builtin_amdgcn_mfma_f32_16x16x32_bf16(a1, b1, acc, 0, 0, 0);
#pragma unroll
      for (int r = 0; r < 4; ++r)
        Os[t][(rbase + quad * 4 + r) * 64 + j * 16 + l16] = f2b(acc[r]);
    }
  }
}

// ---------------- MFMA flash attention (causal) ----------------
// q,k: [B,S,H,D] bf16; vt: [B,H,D,S] bf16 (pre-transposed). o: [B,S,H,D].
__global__ __launch_bounds__(256) void k_attn_mfma(const u16* __restrict__ q,
                                                   const u16* __restrict__ kk,
                                                   const u16* __restrict__ vt,
                                                   u16* __restrict__ o) {
  constexpr int LDK = 72;  // row stride (u16): 144 B -> b128-aligned rows, non-pow2 banks
  __shared__ u16 Ks[64 * LDK];      // [key][d]
  __shared__ u16 Vt[64 * LDK];      // [d][key]
  __shared__ u16 Ps[4][16 * LDK];   // per-wave P [qrow][key]
  int tid = threadIdx.x, lane = tid & 63, wave = tid >> 6;
  int quad = lane >> 4, l16 = lane & 15;
  int b = blockIdx.x >> 4, h = blockIdx.x & 15;
  int qi = (int)gridDim.y - 1 - (int)blockIdx.y;  // heavy q-tiles dispatch first
  int q0 = qi * 64 + wave * 16;

  const u16* qp = q + (((long)(b * 1024 + q0 + l16)) * 16 + h) * 64;
  s8v aq0 = *(const s8v*)(qp + quad * 8);
  s8v aq1 = *(const s8v*)(qp + 32 + quad * 8);

  f4 O[4];
  float m_[4], l_[4];
#pragma unroll
  for (int jd = 0; jd < 4; ++jd) O[jd] = f4{0.f, 0.f, 0.f, 0.f};
#pragma unroll
  for (int r = 0; r < 4; ++r) { m_[r] = -__builtin_inff(); l_[r] = 0.f; }

  for (int kt = 0; kt <= qi; ++kt) {
    __syncthreads();  // protect Ks/Vt reuse across tiles
#pragma unroll
    for (int p = 0; p < 2; ++p) {
      int idx = p * 256 + tid;
      int row = idx >> 3, c8 = (idx & 7) * 8;
      *(s8v*)(Ks + row * LDK + c8) =
          *(const s8v*)(kk + (((long)(b * 1024 + kt * 64 + row)) * 16 + h) * 64 + c8);
      *(s8v*)(Vt + row * LDK + c8) =
          *(const s8v*)(vt + ((long)blockIdx.x * 64 + row) * 1024 + kt * 64 + c8);
    }
    __syncthreads();

    // ---- S = Q K^T ----
    f4 sf[4];
#pragma unroll
    for (int jn = 0; jn < 4; ++jn) {
      s8v b0 = *(const s8v*)(Ks + (jn * 16 + l16) * LDK + quad * 8);
      s8v b1 = *(const s8v*)(Ks + (jn * 16 + l16) * LDK + 32 + quad * 8);
      f4 acc = f4{0.f, 0.f, 0.f, 0.f};
      acc = __builtin_amdgcn_mfma_f32_16x16x32_bf16(aq0, b0, acc, 0, 0, 0);
      acc = __builtin_amdgcn_mfma_f32_16x16x32_bf16(aq1, b1, acc, 0, 0, 0);
      sf[jn] = acc;
    }
    bool diag = (kt == qi);
    float rm[4];
#pragma unroll
    for (int r = 0; r < 4; ++r) rm[r] = -__builtin_inff();
#pragma unroll
    for (int jn = 0; jn < 4; ++jn)
#pragma unroll
      for (int r = 0; r < 4; ++r) {
        float v = sf[jn][r] * 0.03125f;
        if (diag && (jn * 16 + l16 > wave * 16 + quad * 4 + r)) v = -__builtin_inff();
        sf[jn][r] = v;
        rm[r] = fmaxf(rm[r], v);
      }
#pragma unroll
    for (int off = 1; off < 16; off <<= 1)
#pragma unroll
      for (int r = 0; r < 4; ++r) rm[r] = fmaxf(rm[r], __shfl_xor(rm[r], off, 64));
    float alpha[4], rs[4];
#pragma unroll
    for (int r = 0; r < 4; ++r) {
      float mn = fmaxf(m_[r], rm[r]);
      alpha[r] = __expf(m_[r] - mn);
      m_[r] = mn;
      rs[r] = 0.f;
    }
#pragma unroll
    for (int jn = 0; jn < 4; ++jn)
#pragma unroll
      for (int r = 0; r < 4; ++r) {
        float p = __expf(sf[jn][r] - m_[r]);
        rs[r] += p;
        Ps[wave][(quad * 4 + r) * LDK + jn * 16 + l16] = f2b(p);
      }
#pragma unroll
    for (int off = 1; off < 16; off <<= 1)
#pragma unroll
      for (int r = 0; r < 4; ++r) rs[r] += __shfl_xor(rs[r], off, 64);
#pragma unroll
    for (int r = 0; r < 4; ++r) l_[r] = l_[r] * alpha[r] + rs[r];
#pragma unroll
    for (int jd = 0; jd < 4; ++jd)
#pragma unroll
      for (int r = 0; r < 4; ++r) O[jd][r] *= alpha[r];
    asm volatile("s_waitcnt lgkmcnt(0)" ::: "memory");
    s8v p0 = *(const s8v*)(&Ps[wave][l16 * LDK + quad * 8]);
    s8v p1 = *(const s8v*)(&Ps[wave][l16 * LDK + 32 + quad * 8]);
#pragma unroll
    for (int jd = 0; jd < 4; ++jd) {
      s8v b0 = *(const s8v*)(Vt + (jd * 16 + l16) * LDK + quad * 8);
      s8v b1 = *(const s8v*)(Vt + (jd * 16 + l16) * LDK + 32 + quad * 8);
      O[jd] = __builtin_amdgcn_mfma_f32_16x16x32_bf16(p0, b0, O[jd], 0, 0, 0);
      O[jd] = __builtin_amdgcn_mfma_f32_16x16x32_bf16(p1, b1, O[jd], 0, 0, 0);
    }
  }
#pragma unroll
  for (int r = 0; r < 4; ++r) {
    float inv = 1.0f / l_[r];
    u16* op = o + (((long)(b * 1024 + q0 + quad * 4 + r)) * 16 + h) * 64;
#pragma unroll
    for (int jd = 0; jd < 4; ++jd) op[jd * 16 + l16] = f2b(O[jd][r] * inv);
  }
}

// ---------------- 128x128 GEMM, TRIPLE-buffered GLD_LDS, vmcnt(4) barrier ----------------
// A[M,K] bf16, BT[N,K] bf16, fp32 acc.
// EPI=1: out = bf16(relu(acc+bias));  EPI=2: out = fp32(resid + acc + bias)
// AITER-style pipeline with zero VALU staging cost: tile t+2's global_load_lds
// (4 per tile) are issued at iter t; the barrier uses raw
// `s_waitcnt vmcnt(4); s_barrier` — waits only for the OLDEST 4 DMA loads
// (tile t, issued two iterations ago), leaving tile t+1's loads in flight
// across the barrier. Safety: a wave's ds_reads of buf[(t+2)%3] at iter t-1
// are lgkm-retired before its MFMAs, which precede the iter-t barrier; the
// overwrite of that buffer is issued only after the barrier. Final 2 iters
// (no more prefetch) drain with vmcnt(0).
template <int EPI>
__global__ __launch_bounds__(256) void k_gemm_bt(const u16* __restrict__ A, const u16* __restrict__ BT,
                                                 const float* __restrict__ bias,
                                                 const float* __restrict__ resid,
                                                 void* __restrict__ outp, int M, int N, int K) {
  __shared__ u16 sA[3][128 * 32];  // 48 KB total (A+B): 3 blocks/CU by LDS
  __shared__ u16 sB[3][128 * 32];
  int tid = threadIdx.x, lane = tid & 63, wave = tid >> 6;
  int quad = lane >> 4, l16 = lane & 15;
  int wm = wave >> 1, wn = wave & 1;
  long bm = blockIdx.x, bn = blockIdx.y;
  int srow = tid >> 2, scol = (tid & 3) * 8;  // LDS dest byte off = tid*16 (lane-linear)
  const u16* ga = A + (bm * 128 + srow) * (long)K + scol;
  const u16* gb = BT + (bn * 128 + srow) * (long)K + scol;
  int woff = wave * 1024;  // wave-uniform LDS base (64 lanes x 16 B)

  f4 acc[4][4];
#pragma unroll
  for (int i = 0; i < 4; ++i)
#pragma unroll
    for (int j = 0; j < 4; ++j) acc[i][j] = f4{0.f, 0.f, 0.f, 0.f};

  // prologue: tiles 0 and 1 into bufs 0 and 1 (8 loads outstanding)
#pragma unroll
  for (int t = 0; t < 2; ++t) {
    char* lA = (char*)&sA[t][0] + woff;
    char* lB = (char*)&sB[t][0] + woff;
    GLD_LDS16(ga + t * 32, lA);
    GLD_LDS16(ga + 64 * (long)K + t * 32, lA + 4096);
    GLD_LDS16(gb + t * 32, lB);
    GLD_LDS16(gb + 64 * (long)K + t * 32, lB + 4096);
  }

  int cur = 0;
  for (int k0 = 0; k0 < K; k0 += 32) {
    int k2 = k0 + 64;
    if (k2 < K) {
      // tile t+1 (4 loads) stays in flight across the barrier
      asm volatile("s_waitcnt vmcnt(4)\n\ts_barrier" ::: "memory");
      int nb = cur >= 1 ? cur - 1 : 2;  // (cur+2)%3
      char* lA = (char*)&sA[nb][0] + woff;
      char* lB = (char*)&sB[nb][0] + woff;
      GLD_LDS16(ga + k2, lA);
      GLD_LDS16(ga + 64 * (long)K + k2, lA + 4096);
      GLD_LDS16(gb + k2, lB);
      GLD_LDS16(gb + 64 * (long)K + k2, lB + 4096);
    } else {
      asm volatile("s_waitcnt vmcnt(0)\n\ts_barrier" ::: "memory");
    }
    const u16* cA = sA[cur];
    const u16* cB = sB[cur];
    s8v aF[4], bF[4];
#pragma unroll
    for (int i = 0; i < 4; ++i)
      aF[i] = *(const s8v*)(cA + (wm * 64 + i * 16 + l16) * 32 + quad * 8);
#pragma unroll
    for (int j = 0; j < 4; ++j)
      bF[j] = *(const s8v*)(cB + (wn * 64 + j * 16 + l16) * 32 + quad * 8);
#pragma unroll
    for (int i = 0; i < 4; ++i)
#pragma unroll
      for (int j = 0; j < 4; ++j)
        acc[i][j] = __builtin_amdgcn_mfma_f32_16x16x32_bf16(aF[i], bF[j], acc[i][j], 0, 0, 0);
    cur = cur < 2 ? cur + 1 : 0;
  }

#pragma unroll
  for (int i = 0; i < 4; ++i) {
#pragma unroll
    for (int j = 0; j < 4; ++j) {
      long row = bm * 128 + wm * 64 + i * 16 + quad * 4;
      int col = (int)bn * 128 + wn * 64 + j * 16 + l16;
      float bcol = bias[col];
#pragma unroll
      for (int r = 0; r < 4; ++r) {
        float val = acc[i][j][r] + bcol;
        if (EPI == 1) {
          ((u16*)outp)[(row + r) * (long)N + col] = f2b(val > 0.f ? val : 0.f);
        } else {
          ((float*)outp)[(row + r) * (long)N + col] = resid[(row + r) * (long)N + col] + val;
        }
      }
    }
  }
}

extern "C" void kernel_launch(void* const* d_in, const int* in_sizes, int n_in, void* d_out,
                              int out_size, void* d_ws, size_t ws_size, hipStream_t stream) {
  const float* x = (const float*)d_in[0];
  const float* Wq = (const float*)d_in[1];
  const float* Wk = (const float*)d_in[2];
  const float* Wv = (const float*)d_in[3];
  const float* Wo = (const float*)d_in[4];
  const float* bo = (const float*)d_in[5];
  const float* W1 = (const float*)d_in[6];
  const float* b1 = (const float*)d_in[7];
  const float* W2 = (const float*)d_in[8];
  const float* b2 = (const float*)d_in[9];
  const float* g1 = (const float*)d_in[10];
  const float* be1 = (const float*)d_in[11];
  const float* g2 = (const float*)d_in[12];
  const float* be2 = (const float*)d_in[13];

  char* ws = (char*)d_ws;
  const size_t MB = 1ull << 20;
  u16* nx = (u16*)(ws + 0);            // 16 MB  LN1 out; reused as attn out
  u16* qb = (u16*)(ws + 16 * MB);      // 16 MB  q; reused as nx2
  u16* kb = (u16*)(ws + 32 * MB);      // 16 MB
  u16* vb = (u16*)(ws + 48 * MB);      // 16 MB
  float* x1 = (float*)(ws + 64 * MB);  // 32 MB  attn-sublayer output (fp32 residual)
  u16* h1 = (u16*)(ws + 96 * MB);      // 64 MB  MLP hidden (after attn)
  u16* vtr = (u16*)(ws + 96 * MB);     // 16 MB  V^T [B,H,D,S]; dead before h1 is written
  u16* WoT = (u16*)(ws + 160 * MB);    // 2 MB
  u16* W1T = (u16*)(ws + 162 * MB);    // 8 MB
  u16* W2T = (u16*)(ws + 170 * MB);    // 8 MB
  u16* WqT = (u16*)(ws + 178 * MB);
  u16* WkT = WqT + 64 * 64;
  u16* WvT = WkT + 64 * 64;
  u16* ob = nx;
  u16* nx2 = qb;

  k_transpose<<<dim3(32, 32), 256, 0, stream>>>(Wo, WoT, 1024, 1024);
  k_transpose<<<dim3(128, 32), 256, 0, stream>>>(W1, W1T, 1024, 4096);
  k_transpose<<<dim3(32, 128), 256, 0, stream>>>(W2, W2T, 4096, 1024);
  k_transpose<<<dim3(2, 2), 256, 0, stream>>>(Wq, WqT, 64, 64);
  k_transpose<<<dim3(2, 2), 256, 0, stream>>>(Wk, WkT, 64, 64);
  k_transpose<<<dim3(2, 2), 256, 0, stream>>>(Wv, WvT, 64, 64);

  k_layernorm<<<8192, 256, 0, stream>>>(x, g1, be1, nx);
  k_qkv<<<2048, 256, 0, stream>>>(nx, WqT, WkT, WvT, qb, kb, vb);
  k_vtrans<<<dim3(128, 16), 256, 0, stream>>>(vb, vtr);
  k_attn_mfma<<<dim3(128, 16), 256, 0, stream>>>(qb, kb, vtr, ob);
  k_gemm_bt<2><<<dim3(64, 8), 256, 0, stream>>>(ob, WoT, bo, x, x1, 8192, 1024, 1024);

  k_layernorm<<<8192, 256, 0, stream>>>(x1, g2, be2, nx2);
  k_gemm_bt<1><<<dim3(64, 32), 256, 0, stream>>>(nx2, W1T, b1, nullptr, h1, 8192, 4096, 1024);
  k_gemm_bt<2><<<dim3(64, 8), 256, 0, stream>>>(h1, W2T, b2, x1, d_out, 8192, 1024, 4096);
}